// Round 6
// baseline (2047.367 us; speedup 1.0000x reference)
//
#include <hip/hip_runtime.h>
#include <stdint.h>

typedef __bf16 bf16x8 __attribute__((ext_vector_type(8)));
typedef float  f32x4  __attribute__((ext_vector_type(4)));

#define PRED   200
#define TSTEPS 200
#define NBLK   256
#define ABUFB  8192                 // 16 rows x 256 cols x 2B, XOR-swizzled, no pad
// k_l1 LDS: W(wih1-hi frag-linear) + A0 + A1 + ST
#define L1_A_OFF   131072
#define L1_ST_OFF  (131072 + 2*ABUFB)
#define LDS_L1     (131072 + 3*ABUFB)   // 155648
#define LDS_SMALL  (2*ABUFB)            // k_l0 / k_dec: 16384

#define STATE_FLOATS ((size_t)NBLK*4*2048)   // planes: 0=h0,1=c0,2=h1,3=c1

__device__ __forceinline__ float sigm(float x){ return 1.0f/(1.0f+__expf(-x)); }
__device__ __forceinline__ float tanhx(float x){
  float t=__expf(-2.0f*fabsf(x)); float y=(1.0f-t)/(1.0f+t); return copysignf(y,x);
}
__device__ __forceinline__ bf16x8 hi8(float4 a, float4 b){
  bf16x8 r; r[0]=(__bf16)a.x; r[1]=(__bf16)a.y; r[2]=(__bf16)a.z; r[3]=(__bf16)a.w;
  r[4]=(__bf16)b.x; r[5]=(__bf16)b.y; r[6]=(__bf16)b.z; r[7]=(__bf16)b.w; return r;
}
__device__ __forceinline__ bf16x8 lo8(float4 a, float4 b, bf16x8 h){
  bf16x8 r;
  r[0]=(__bf16)(a.x-(float)h[0]); r[1]=(__bf16)(a.y-(float)h[1]);
  r[2]=(__bf16)(a.z-(float)h[2]); r[3]=(__bf16)(a.w-(float)h[3]);
  r[4]=(__bf16)(b.x-(float)h[4]); r[5]=(__bf16)(b.y-(float)h[5]);
  r[6]=(__bf16)(b.z-(float)h[6]); r[7]=(__bf16)(b.w-(float)h[7]); return r;
}
#define MFMA(A,B,C) __builtin_amdgcn_mfma_f32_16x16x32_bf16((A),(B),(C),0,0,0)

// XOR-swizzled A-buffer addressing. col: 0..127 = hi plane, 128..255 = lo plane.
__device__ __forceinline__ int aoff(int row, int col){
  return row*512 + ((((col>>3) ^ (row&7)) << 4) | ((col&7)<<1));
}
// b128 fragment read: row=c, col8 block = kt*4+qd (+16 for lo plane)
__device__ __forceinline__ int frdoff(int c, int qd, int kt, int plane){
  return c*512 + (((((kt<<2)+qd) ^ (c&7)) | (plane<<4)) << 4);
}

// ======================= layer-0 recurrent (per T-chunk) =======================
__global__ void __launch_bounds__(512,2)
k_l0(const float* __restrict__ xh, const float* __restrict__ wih0,
     const float* __restrict__ whh0, const float* __restrict__ bih0,
     const float* __restrict__ bhh0, float* __restrict__ wsf,
     int chunkStart, int chunkLen, unsigned long long stageFloats)
{
  extern __shared__ char smem[];
  const int tid=threadIdx.x, wv=tid>>6, l=tid&63, c=l&15, qd=l>>4;
  const int hc=wv*16+c, blk=blockIdx.x, r0=blk*16;
  float* stf = wsf + stageFloats;
  // W_hh0 hi+lo fragments in VGPRs
  bf16x8 whi[16], wlo[16];
  #pragma unroll
  for (int tt=0;tt<4;++tt)
    #pragma unroll
    for (int kt=0;kt<4;++kt){
      const float* s=whh0+(size_t)(tt*128+hc)*128+kt*32+qd*8;
      float4 a=*(const float4*)s, b=*(const float4*)(s+4);
      whi[tt*4+kt]=hi8(a,b); wlo[tt*4+kt]=lo8(a,b,whi[tt*4+kt]);
    }
  float b0[4], w0x[4], w0y[4];
  #pragma unroll
  for (int tt=0;tt<4;++tt){
    int g=tt*128+hc;
    b0[tt]=bih0[g]+bhh0[g]; w0x[tt]=wih0[2*g]; w0y[tt]=wih0[2*g+1];
  }
  float c0[4];
  {
    char* B1=smem+ABUFB;   // buffer 1: first read target
    const float* hst=stf+(size_t)(blk*4+0)*2048;
    const float* cst=stf+(size_t)(blk*4+1)*2048;
    #pragma unroll
    for (int i=0;i<4;++i){
      int e=tid*4+i, row=e>>7, col=e&127;
      float v=0.f; if(chunkStart) v=hst[e];
      __bf16 h=(__bf16)v;
      *(__bf16*)(B1+aoff(row,col))=h;
      *(__bf16*)(B1+aoff(row,col+128))=(__bf16)(v-(float)h);
    }
    #pragma unroll
    for (int j=0;j<4;++j){ float v=0.f; if(chunkStart) v=cst[(qd*4+j)*128+hc]; c0[j]=v; }
  }
  __syncthreads();
  for (int t=0;t<chunkLen;++t){
    const int p=t&1, tg=chunkStart+t;
    float2 xv[4];
    #pragma unroll
    for (int j=0;j<4;++j) xv[j]=*(const float2*)(xh+(size_t)(r0+qd*4+j)*400+tg*2);
    f32x4 acc[4];
    #pragma unroll
    for (int tt=0;tt<4;++tt) acc[tt]=(f32x4){b0[tt],b0[tt],b0[tt],b0[tt]};
    const char* Ar=smem+(size_t)(1-p)*ABUFB;
    #pragma unroll
    for (int kt=0;kt<4;++kt){
      bf16x8 ah=*(const bf16x8*)(Ar+frdoff(c,qd,kt,0));
      bf16x8 al=*(const bf16x8*)(Ar+frdoff(c,qd,kt,1));
      #pragma unroll
      for (int tt=0;tt<4;++tt){
        acc[tt]=MFMA(ah,whi[tt*4+kt],acc[tt]);
        acc[tt]=MFMA(al,whi[tt*4+kt],acc[tt]);
        acc[tt]=MFMA(ah,wlo[tt*4+kt],acc[tt]);
      }
    }
    char* Aw=smem+(size_t)p*ABUFB;
    float* h0o=wsf+((size_t)t*NBLK+blk)*2048;
    #pragma unroll
    for (int j=0;j<4;++j){
      float gi=acc[0][j]+xv[j].x*w0x[0]+xv[j].y*w0y[0];
      float gf=acc[1][j]+xv[j].x*w0x[1]+xv[j].y*w0y[1];
      float gg=acc[2][j]+xv[j].x*w0x[2]+xv[j].y*w0y[2];
      float go=acc[3][j]+xv[j].x*w0x[3]+xv[j].y*w0y[3];
      float cn=sigm(gf)*c0[j]+sigm(gi)*tanhx(gg); c0[j]=cn;
      float hn=sigm(go)*tanhx(cn);
      int row=qd*4+j;
      __bf16 hh=(__bf16)hn;
      *(__bf16*)(Aw+aoff(row,hc))=hh;
      *(__bf16*)(Aw+aoff(row,hc+128))=(__bf16)(hn-(float)hh);
      h0o[row*128+hc]=hn;
      if (t==chunkLen-1){
        stf[(size_t)(blk*4+0)*2048+row*128+hc]=hn;
        stf[(size_t)(blk*4+1)*2048+row*128+hc]=cn;
      }
    }
    __syncthreads();
  }
}

// ======================= layer-1 recurrent (per T-chunk) =======================
__global__ void __launch_bounds__(512,2)
k_l1(const float* __restrict__ wih1, const float* __restrict__ whh1,
     const float* __restrict__ bih1, const float* __restrict__ bhh1,
     float* __restrict__ wsf, int chunkStart, int chunkLen,
     unsigned long long stageFloats)
{
  extern __shared__ char smem[];
  const int tid=threadIdx.x, wv=tid>>6, l=tid&63, c=l&15, qd=l>>4;
  const int hc=wv*16+c, blk=blockIdx.x;
  float* stf = wsf + stageFloats;
  // cook W_ih1 hi -> LDS, fragment-linear (conflict-free b128 reads)
  #pragma unroll
  for (int i=0;i<16;++i){
    int f=i*8+wv, ntg=f>>2, kt=f&3;
    int g=(ntg&3)*128+(ntg>>2)*16+c, k=kt*32+qd*8;
    const float* s=wih1+g*128+k;
    *(bf16x8*)(smem+f*1024+l*16)=hi8(*(const float4*)s,*(const float4*)(s+4));
  }
  // wih1-lo, whh1-hi, whh1-lo fragments in VGPRs (192 regs)
  bf16x8 wil[16], whh[16], whl[16];
  #pragma unroll
  for (int tt=0;tt<4;++tt)
    #pragma unroll
    for (int kt=0;kt<4;++kt){
      const float* s=wih1+(size_t)(tt*128+hc)*128+kt*32+qd*8;
      float4 a=*(const float4*)s, b=*(const float4*)(s+4);
      wil[tt*4+kt]=lo8(a,b,hi8(a,b));
      const float* s2=whh1+(size_t)(tt*128+hc)*128+kt*32+qd*8;
      float4 a2=*(const float4*)s2, b2=*(const float4*)(s2+4);
      bf16x8 h2=hi8(a2,b2);
      whh[tt*4+kt]=h2; whl[tt*4+kt]=lo8(a2,b2,h2);
    }
  float b1v[4];
  #pragma unroll
  for (int tt=0;tt<4;++tt){ int g=tt*128+hc; b1v[tt]=bih1[g]+bhh1[g]; }
  float c1[4];
  {
    char* B1=smem+L1_A_OFF+ABUFB;
    const float* hst=stf+(size_t)(blk*4+2)*2048;
    const float* cst=stf+(size_t)(blk*4+3)*2048;
    #pragma unroll
    for (int i=0;i<4;++i){
      int e=tid*4+i, row=e>>7, col=e&127;
      float v=0.f; if(chunkStart) v=hst[e];
      __bf16 h=(__bf16)v;
      *(__bf16*)(B1+aoff(row,col))=h;
      *(__bf16*)(B1+aoff(row,col+128))=(__bf16)(v-(float)h);
    }
    #pragma unroll
    for (int j=0;j<4;++j){ float v=0.f; if(chunkStart) v=cst[(qd*4+j)*128+hc]; c1[j]=v; }
  }
  float4 r4=*(const float4*)(wsf+((size_t)0*NBLK+blk)*2048+tid*4);
  __syncthreads();
  for (int t=0;t<chunkLen;++t){
    const int p=t&1;
    {
      char* ST=smem+L1_ST_OFF;
      int e=tid*4, row=e>>7, col=e&127;
      #pragma unroll
      for (int i=0;i<4;++i){
        float v=r4[i]; __bf16 h=(__bf16)v;
        *(__bf16*)(ST+aoff(row,col+i))=h;
        *(__bf16*)(ST+aoff(row,col+i+128))=(__bf16)(v-(float)h);
      }
    }
    if (t+1<chunkLen) r4=*(const float4*)(wsf+((size_t)(t+1)*NBLK+blk)*2048+tid*4);
    __syncthreads();
    f32x4 acc[4];
    #pragma unroll
    for (int tt=0;tt<4;++tt) acc[tt]=(f32x4){b1v[tt],b1v[tt],b1v[tt],b1v[tt]};
    const char* Ar=smem+L1_A_OFF+(size_t)(1-p)*ABUFB;
    const char* Sr=smem+L1_ST_OFF;
    #pragma unroll
    for (int kt=0;kt<4;++kt){
      bf16x8 a0h=*(const bf16x8*)(Sr+frdoff(c,qd,kt,0));
      bf16x8 a0l=*(const bf16x8*)(Sr+frdoff(c,qd,kt,1));
      bf16x8 a1h=*(const bf16x8*)(Ar+frdoff(c,qd,kt,0));
      bf16x8 a1l=*(const bf16x8*)(Ar+frdoff(c,qd,kt,1));
      #pragma unroll
      for (int tt=0;tt<4;++tt){
        bf16x8 bh=*(const bf16x8*)(smem+(size_t)((wv*4+tt)*4+kt)*1024+l*16);
        acc[tt]=MFMA(a0h,bh,acc[tt]);
        acc[tt]=MFMA(a0l,bh,acc[tt]);
        acc[tt]=MFMA(a0h,wil[tt*4+kt],acc[tt]);
        acc[tt]=MFMA(a1h,whh[tt*4+kt],acc[tt]);
        acc[tt]=MFMA(a1l,whh[tt*4+kt],acc[tt]);
        acc[tt]=MFMA(a1h,whl[tt*4+kt],acc[tt]);
      }
    }
    char* Aw=smem+L1_A_OFF+(size_t)p*ABUFB;
    #pragma unroll
    for (int j=0;j<4;++j){
      float cn=sigm(acc[1][j])*c1[j]+sigm(acc[0][j])*tanhx(acc[2][j]); c1[j]=cn;
      float hn=sigm(acc[3][j])*tanhx(cn);
      int row=qd*4+j;
      __bf16 hh=(__bf16)hn;
      *(__bf16*)(Aw+aoff(row,hc))=hh;
      *(__bf16*)(Aw+aoff(row,hc+128))=(__bf16)(hn-(float)hh);
      if (t==chunkLen-1){
        stf[(size_t)(blk*4+2)*2048+row*128+hc]=hn;
        stf[(size_t)(blk*4+3)*2048+row*128+hc]=cn;
      }
    }
    __syncthreads();
  }
}

// ======================= decoder (200 autoregressive steps) =======================
__global__ void __launch_bounds__(512,2)
k_dec(const float* __restrict__ xh, const float* __restrict__ pprm,
      const float* __restrict__ dwihp, const float* __restrict__ dwhh,
      const float* __restrict__ dbih, const float* __restrict__ dbhh,
      const float* __restrict__ pw, const float* __restrict__ pb,
      const float* __restrict__ ow, const float* __restrict__ ob,
      const float* __restrict__ wsf, float* __restrict__ out,
      unsigned long long stageFloats)
{
  extern __shared__ char smem[];
  const int tid=threadIdx.x, wv=tid>>6, l=tid&63, c=l&15, qd=l>>4;
  const int hc=wv*16+c, blk=blockIdx.x, r0=blk*16;
  const float* stf = wsf + stageFloats;
  // dec_w_hh hi+lo fragments in VGPRs
  bf16x8 whi[16], wlo[16];
  #pragma unroll
  for (int tt=0;tt<4;++tt)
    #pragma unroll
    for (int kt=0;kt<4;++kt){
      const float* s=dwhh+(size_t)(tt*128+hc)*128+kt*32+qd*8;
      float4 a=*(const float4*)s, b=*(const float4*)(s+4);
      whi[tt*4+kt]=hi8(a,b); wlo[tt*4+kt]=lo8(a,b,whi[tt*4+kt]);
    }
  // out_w fragments (B[k][n]=ow[n*128+k], n=c<2 else 0), hi+lo
  bf16x8 owh[4], owl[4];
  #pragma unroll
  for (int kt=0;kt<4;++kt){
    int cc=(c<2)?c:0;
    const float* s=ow+cc*128+kt*32+qd*8;
    float4 a=*(const float4*)s, b=*(const float4*)(s+4);
    if (c>=2){ a=(float4){0,0,0,0}; b=(float4){0,0,0,0}; }
    owh[kt]=hi8(a,b); owl[kt]=lo8(a,b,owh[kt]);
  }
  float ob0=ob[0], ob1=ob[1];
  // gate constants: pt[tt][j] = bias + params-term; dw0/dw1 per gate-col
  float prm[4][3];
  #pragma unroll
  for (int j=0;j<4;++j){
    size_t r=(size_t)(r0+qd*4+j);
    prm[j][0]=pprm[r*3+0]; prm[j][1]=pprm[r*3+1]; prm[j][2]=pprm[r*3+2];
  }
  float pt[4][4], dw0[4], dw1[4];
  #pragma unroll
  for (int tt=0;tt<4;++tt){
    int g=tt*128+hc;
    float db=dbih[g]+dbhh[g];
    dw0[tt]=dwihp[g*5+0]; dw1[tt]=dwihp[g*5+1];
    #pragma unroll
    for (int j=0;j<4;++j)
      pt[tt][j]=db+prm[j][0]*dwihp[g*5+2]+prm[j][1]*dwihp[g*5+3]+prm[j][2]*dwihp[g*5+4];
  }
  // init: h_dec -> A[0], c_dec, cur_0 from x_hist last frame
  const float* h1s=stf+(size_t)(blk*4+2)*2048;
  const float* c1s=stf+(size_t)(blk*4+3)*2048;
  float c1[4], cx0[4], cx1[4];
  {
    float prj0=pw[hc*3+0], prj1=pw[hc*3+1], prj2=pw[hc*3+2], prjb=pb[hc];
    char* B0=smem;
    #pragma unroll
    for (int j=0;j<4;++j){
      int row=qd*4+j;
      float hd=h1s[row*128+hc]+prm[j][0]*prj0+prm[j][1]*prj1+prm[j][2]*prj2+prjb;
      __bf16 h=(__bf16)hd;
      *(__bf16*)(B0+aoff(row,hc))=h;
      *(__bf16*)(B0+aoff(row,hc+128))=(__bf16)(hd-(float)h);
      c1[j]=c1s[row*128+hc];
      float2 xx=*(const float2*)(xh+(size_t)(r0+row)*400+398);
      cx0[j]=xx.x; cx1[j]=xx.y;
    }
  }
  __syncthreads();
  for (int s=0;s<PRED;++s){
    const int q=s&1;
    const char* Ar=smem+(size_t)q*ABUFB;
    f32x4 acc[4], accPV={0.f,0.f,0.f,0.f};
    #pragma unroll
    for (int tt=0;tt<4;++tt) acc[tt]=(f32x4){pt[tt][0],pt[tt][1],pt[tt][2],pt[tt][3]};
    #pragma unroll
    for (int kt=0;kt<4;++kt){
      bf16x8 ah=*(const bf16x8*)(Ar+frdoff(c,qd,kt,0));
      bf16x8 al=*(const bf16x8*)(Ar+frdoff(c,qd,kt,1));
      #pragma unroll
      for (int tt=0;tt<4;++tt){
        acc[tt]=MFMA(ah,whi[tt*4+kt],acc[tt]);
        acc[tt]=MFMA(al,whi[tt*4+kt],acc[tt]);
        acc[tt]=MFMA(ah,wlo[tt*4+kt],acc[tt]);
      }
      accPV=MFMA(ah,owh[kt],accPV);
      accPV=MFMA(al,owh[kt],accPV);
      accPV=MFMA(ah,owl[kt],accPV);
    }
    // cur for this step: s==0 -> x last frame; else ow.h_{s-1}+ob via intra-wave broadcast
    float cur0[4], cur1[4];
    #pragma unroll
    for (int j=0;j<4;++j){
      float pv0=__shfl(accPV[j], (l&48),   64);
      float pv1=__shfl(accPV[j], (l&48)|1, 64);
      cur0[j]= s ? (pv0+ob0) : cx0[j];
      cur1[j]= s ? (pv1+ob1) : cx1[j];
    }
    if (s && wv==0 && c<2){
      float obv=c?ob1:ob0;
      #pragma unroll
      for (int j=0;j<4;++j)
        out[(size_t)(r0+qd*4+j)*400+(s-1)*2+c]=accPV[j]+obv;
    }
    char* Aw=smem+(size_t)(1-q)*ABUFB;
    #pragma unroll
    for (int j=0;j<4;++j){
      float gi=acc[0][j]+cur0[j]*dw0[0]+cur1[j]*dw1[0];
      float gf=acc[1][j]+cur0[j]*dw0[1]+cur1[j]*dw1[1];
      float gg=acc[2][j]+cur0[j]*dw0[2]+cur1[j]*dw1[2];
      float go=acc[3][j]+cur0[j]*dw0[3]+cur1[j]*dw1[3];
      float cn=sigm(gf)*c1[j]+sigm(gi)*tanhx(gg); c1[j]=cn;
      float hn=sigm(go)*tanhx(cn);
      int row=qd*4+j;
      __bf16 hh=(__bf16)hn;
      *(__bf16*)(Aw+aoff(row,hc))=hh;
      *(__bf16*)(Aw+aoff(row,hc+128))=(__bf16)(hn-(float)hh);
    }
    __syncthreads();
  }
  // epilogue: out[PRED-1] = ow.h_{PRED-1}+ob from A[PRED&1]
  {
    const char* Ar=smem+(size_t)(PRED&1)*ABUFB;
    f32x4 accPV={0.f,0.f,0.f,0.f};
    #pragma unroll
    for (int kt=0;kt<4;++kt){
      bf16x8 ah=*(const bf16x8*)(Ar+frdoff(c,qd,kt,0));
      bf16x8 al=*(const bf16x8*)(Ar+frdoff(c,qd,kt,1));
      accPV=MFMA(ah,owh[kt],accPV);
      accPV=MFMA(al,owh[kt],accPV);
      accPV=MFMA(ah,owl[kt],accPV);
    }
    if (wv==0 && c<2){
      float obv=c?ob1:ob0;
      #pragma unroll
      for (int j=0;j<4;++j)
        out[(size_t)(r0+qd*4+j)*400+(PRED-1)*2+c]=accPV[j]+obv;
    }
  }
}

extern "C" void kernel_launch(void* const* d_in, const int* in_sizes, int n_in,
                              void* d_out, int out_size, void* d_ws, size_t ws_size,
                              hipStream_t stream)
{
  (void)out_size;
  const int base = (n_in >= 19 && in_sizes[2] == 1) ? 3 : 2;
  const float* xh   = (const float*)d_in[0];
  const float* prm  = (const float*)d_in[1];
  const float* wih0 = (const float*)d_in[base+0];
  const float* whh0 = (const float*)d_in[base+1];
  const float* bih0 = (const float*)d_in[base+2];
  const float* bhh0 = (const float*)d_in[base+3];
  const float* wih1 = (const float*)d_in[base+4];
  const float* whh1 = (const float*)d_in[base+5];
  const float* bih1 = (const float*)d_in[base+6];
  const float* bhh1 = (const float*)d_in[base+7];
  const float* dwih = (const float*)d_in[base+8];
  const float* dwhh = (const float*)d_in[base+9];
  const float* dbih = (const float*)d_in[base+10];
  const float* dbhh = (const float*)d_in[base+11];
  const float* pw   = (const float*)d_in[base+12];
  const float* pb   = (const float*)d_in[base+13];
  const float* ow   = (const float*)d_in[base+14];
  const float* ob   = (const float*)d_in[base+15];
  float* wsf = (float*)d_ws;

  size_t wsFloats = ws_size / 4;
  size_t avail = (wsFloats > STATE_FLOATS) ? (wsFloats - STATE_FLOATS) : 0;
  int chunkLen = (int)(avail / ((size_t)NBLK * 2048));
  if (chunkLen > 50) chunkLen = 50;
  if (chunkLen < 1)  chunkLen = 1;
  unsigned long long stageFloats = (unsigned long long)chunkLen * NBLK * 2048;

  hipFuncSetAttribute((const void*)k_l1, hipFuncAttributeMaxDynamicSharedMemorySize, LDS_L1);

  for (int k0 = 0; k0 < TSTEPS; k0 += chunkLen){
    int len = chunkLen; if (k0 + len > TSTEPS) len = TSTEPS - k0;
    k_l0<<<NBLK,512,LDS_SMALL,stream>>>(xh, wih0, whh0, bih0, bhh0, wsf, k0, len, stageFloats);
    k_l1<<<NBLK,512,LDS_L1,stream>>>(wih1, whh1, bih1, bhh1, wsf, k0, len, stageFloats);
  }
  k_dec<<<NBLK,512,LDS_SMALL,stream>>>(xh, prm, dwih, dwhh, dbih, dbhh,
                                       pw, pb, ow, ob, wsf, (float*)d_out, stageFloats);
}

// Round 7
// 2031.590 us; speedup vs baseline: 1.0078x; 1.0078x over previous
//
#include <hip/hip_runtime.h>
#include <stdint.h>

typedef __bf16 bf16x8 __attribute__((ext_vector_type(8)));
typedef float  f32x4  __attribute__((ext_vector_type(4)));

#define PRED   200
#define TSTEPS 200
#define NBLK   256
#define ABUFB  8192                 // 16 rows x 256 cols x 2B, XOR-swizzled, no pad
#define L1_A_OFF   131072
#define L1_ST_OFF  (131072 + 2*ABUFB)
#define LDS_L1     (131072 + 3*ABUFB)   // 155648
#define LDS_SMALL  (2*ABUFB)            // k_l0 / k_dec: 16384

#define STATE_FLOATS ((size_t)NBLK*4*2048)   // planes: 0=h0,1=c0,2=h1,3=c1

__device__ __forceinline__ float sigm(float x){ return 1.0f/(1.0f+__expf(-x)); }
__device__ __forceinline__ float tanhx(float x){
  float t=__expf(-2.0f*fabsf(x)); float y=(1.0f-t)/(1.0f+t); return copysignf(y,x);
}
__device__ __forceinline__ bf16x8 hi8(float4 a, float4 b){
  bf16x8 r; r[0]=(__bf16)a.x; r[1]=(__bf16)a.y; r[2]=(__bf16)a.z; r[3]=(__bf16)a.w;
  r[4]=(__bf16)b.x; r[5]=(__bf16)b.y; r[6]=(__bf16)b.z; r[7]=(__bf16)b.w; return r;
}
__device__ __forceinline__ bf16x8 lo8(float4 a, float4 b, bf16x8 h){
  bf16x8 r;
  r[0]=(__bf16)(a.x-(float)h[0]); r[1]=(__bf16)(a.y-(float)h[1]);
  r[2]=(__bf16)(a.z-(float)h[2]); r[3]=(__bf16)(a.w-(float)h[3]);
  r[4]=(__bf16)(b.x-(float)h[4]); r[5]=(__bf16)(b.y-(float)h[5]);
  r[6]=(__bf16)(b.z-(float)h[6]); r[7]=(__bf16)(b.w-(float)h[7]); return r;
}
__device__ __forceinline__ uint16_t bfbits(__bf16 x){ union{__bf16 b; uint16_t u;} v; v.b=x; return v.u; }
__device__ __forceinline__ __bf16 bits2bf(uint16_t u){ union{uint16_t u; __bf16 b;} v; v.u=u; return v.b; }
#define MFMA(A,B,C) __builtin_amdgcn_mfma_f32_16x16x32_bf16((A),(B),(C),0,0,0)

// XOR-swizzled A-buffer addressing. col: 0..127 = hi plane, 128..255 = lo plane.
__device__ __forceinline__ int aoff(int row, int col){
  return row*512 + ((((col>>3) ^ (row&7)) << 4) | ((col&7)<<1));
}
__device__ __forceinline__ int frdoff(int c, int qd, int kt, int plane){
  return c*512 + (((((kt<<2)+qd) ^ (c&7)) | (plane<<4)) << 4);
}

// ======================= layer-0 recurrent (per T-chunk) =======================
__global__ void __launch_bounds__(512,1)
k_l0(const float* __restrict__ xh, const float* __restrict__ wih0,
     const float* __restrict__ whh0, const float* __restrict__ bih0,
     const float* __restrict__ bhh0, float* __restrict__ wsf,
     int chunkStart, int chunkLen, unsigned long long stageFloats)
{
  extern __shared__ char smem[];
  const int tid=threadIdx.x, wv=tid>>6, l=tid&63, c=l&15, qd=l>>4;
  const int hc=wv*16+c, blk=blockIdx.x, r0=blk*16;
  float* stf = wsf + stageFloats;
  bf16x8 whi[16], wlo[16];
  #pragma unroll
  for (int tt=0;tt<4;++tt)
    #pragma unroll
    for (int kt=0;kt<4;++kt){
      const float* s=whh0+(size_t)(tt*128+hc)*128+kt*32+qd*8;
      float4 a=*(const float4*)s, b=*(const float4*)(s+4);
      whi[tt*4+kt]=hi8(a,b); wlo[tt*4+kt]=lo8(a,b,whi[tt*4+kt]);
    }
  float b0[4], w0x[4], w0y[4];
  #pragma unroll
  for (int tt=0;tt<4;++tt){
    int g=tt*128+hc;
    b0[tt]=bih0[g]+bhh0[g]; w0x[tt]=wih0[2*g]; w0y[tt]=wih0[2*g+1];
  }
  float c0[4];
  {
    char* B1=smem+ABUFB;
    const float* hst=stf+(size_t)(blk*4+0)*2048;
    const float* cst=stf+(size_t)(blk*4+1)*2048;
    #pragma unroll
    for (int i=0;i<4;++i){
      int e=tid*4+i, row=e>>7, col=e&127;
      float v=0.f; if(chunkStart) v=hst[e];
      __bf16 h=(__bf16)v;
      *(__bf16*)(B1+aoff(row,col))=h;
      *(__bf16*)(B1+aoff(row,col+128))=(__bf16)(v-(float)h);
    }
    #pragma unroll
    for (int j=0;j<4;++j){ float v=0.f; if(chunkStart) v=cst[(qd*4+j)*128+hc]; c0[j]=v; }
  }
  __syncthreads();
  for (int t=0;t<chunkLen;++t){
    const int p=t&1, tg=chunkStart+t;
    float2 xv[4];
    #pragma unroll
    for (int j=0;j<4;++j) xv[j]=*(const float2*)(xh+(size_t)(r0+qd*4+j)*400+tg*2);
    f32x4 acc[4];
    #pragma unroll
    for (int tt=0;tt<4;++tt) acc[tt]=(f32x4){b0[tt],b0[tt],b0[tt],b0[tt]};
    const char* Ar=smem+(size_t)(1-p)*ABUFB;
    #pragma unroll
    for (int kt=0;kt<4;++kt){
      bf16x8 ah=*(const bf16x8*)(Ar+frdoff(c,qd,kt,0));
      bf16x8 al=*(const bf16x8*)(Ar+frdoff(c,qd,kt,1));
      #pragma unroll
      for (int tt=0;tt<4;++tt){
        acc[tt]=MFMA(ah,whi[tt*4+kt],acc[tt]);
        acc[tt]=MFMA(al,whi[tt*4+kt],acc[tt]);
        acc[tt]=MFMA(ah,wlo[tt*4+kt],acc[tt]);
      }
    }
    char* Aw=smem+(size_t)p*ABUFB;
    uint32_t* h0o=(uint32_t*)(wsf+((size_t)t*NBLK+blk)*2048);
    #pragma unroll
    for (int j=0;j<4;++j){
      float gi=acc[0][j]+xv[j].x*w0x[0]+xv[j].y*w0y[0];
      float gf=acc[1][j]+xv[j].x*w0x[1]+xv[j].y*w0y[1];
      float gg=acc[2][j]+xv[j].x*w0x[2]+xv[j].y*w0y[2];
      float go=acc[3][j]+xv[j].x*w0x[3]+xv[j].y*w0y[3];
      float cn=sigm(gf)*c0[j]+sigm(gi)*tanhx(gg); c0[j]=cn;
      float hn=sigm(go)*tanhx(cn);
      int row=qd*4+j;
      __bf16 hh=(__bf16)hn;
      __bf16 hl=(__bf16)(hn-(float)hh);
      *(__bf16*)(Aw+aoff(row,hc))=hh;
      *(__bf16*)(Aw+aoff(row,hc+128))=hl;
      h0o[row*128+hc]=(uint32_t)bfbits(hh) | ((uint32_t)bfbits(hl)<<16);
      if (t==chunkLen-1){
        stf[(size_t)(blk*4+0)*2048+row*128+hc]=hn;
        stf[(size_t)(blk*4+1)*2048+row*128+hc]=cn;
      }
    }
    __syncthreads();
  }
}

// ======================= layer-1 recurrent (per T-chunk) =======================
__global__ void __launch_bounds__(512,1)
k_l1(const float* __restrict__ wih1, const float* __restrict__ whh1,
     const float* __restrict__ bih1, const float* __restrict__ bhh1,
     float* __restrict__ wsf, int chunkStart, int chunkLen,
     unsigned long long stageFloats)
{
  extern __shared__ char smem[];
  const int tid=threadIdx.x, wv=tid>>6, l=tid&63, c=l&15, qd=l>>4;
  const int hc=wv*16+c, blk=blockIdx.x;
  float* stf = wsf + stageFloats;
  #pragma unroll
  for (int i=0;i<16;++i){                    // cook W_ih1 hi -> LDS frag-linear
    int f=i*8+wv, ntg=f>>2, kt=f&3;
    int g=(ntg&3)*128+(ntg>>2)*16+c, k=kt*32+qd*8;
    const float* s=wih1+g*128+k;
    *(bf16x8*)(smem+f*1024+l*16)=hi8(*(const float4*)s,*(const float4*)(s+4));
  }
  bf16x8 wil[16], whh[16], whl[16];
  #pragma unroll
  for (int tt=0;tt<4;++tt)
    #pragma unroll
    for (int kt=0;kt<4;++kt){
      const float* s=wih1+(size_t)(tt*128+hc)*128+kt*32+qd*8;
      float4 a=*(const float4*)s, b=*(const float4*)(s+4);
      wil[tt*4+kt]=lo8(a,b,hi8(a,b));
      const float* s2=whh1+(size_t)(tt*128+hc)*128+kt*32+qd*8;
      float4 a2=*(const float4*)s2, b2=*(const float4*)(s2+4);
      bf16x8 h2=hi8(a2,b2);
      whh[tt*4+kt]=h2; whl[tt*4+kt]=lo8(a2,b2,h2);
    }
  float b1v[4];
  #pragma unroll
  for (int tt=0;tt<4;++tt){ int g=tt*128+hc; b1v[tt]=bih1[g]+bhh1[g]; }
  float c1[4];
  {
    char* B1=smem+L1_A_OFF+ABUFB;
    const float* hst=stf+(size_t)(blk*4+2)*2048;
    const float* cst=stf+(size_t)(blk*4+3)*2048;
    #pragma unroll
    for (int i=0;i<4;++i){
      int e=tid*4+i, row=e>>7, col=e&127;
      float v=0.f; if(chunkStart) v=hst[e];
      __bf16 h=(__bf16)v;
      *(__bf16*)(B1+aoff(row,col))=h;
      *(__bf16*)(B1+aoff(row,col+128))=(__bf16)(v-(float)h);
    }
    #pragma unroll
    for (int j=0;j<4;++j){ float v=0.f; if(chunkStart) v=cst[(qd*4+j)*128+hc]; c1[j]=v; }
  }
  uint4 r4=*(const uint4*)((const uint32_t*)(wsf+((size_t)0*NBLK+blk)*2048)+tid*4);
  __syncthreads();
  for (int t=0;t<chunkLen;++t){
    const int p=t&1;
    {
      char* ST=smem+L1_ST_OFF;
      int e=tid*4, row=e>>7, col=e&127;
      uint32_t uu[4]={r4.x,r4.y,r4.z,r4.w};
      #pragma unroll
      for (int i=0;i<4;++i){
        *(__bf16*)(ST+aoff(row,col+i))=bits2bf((uint16_t)(uu[i]&0xFFFFu));
        *(__bf16*)(ST+aoff(row,col+i+128))=bits2bf((uint16_t)(uu[i]>>16));
      }
    }
    if (t+1<chunkLen) r4=*(const uint4*)((const uint32_t*)(wsf+((size_t)(t+1)*NBLK+blk)*2048)+tid*4);
    __syncthreads();
    f32x4 acc[4];
    #pragma unroll
    for (int tt=0;tt<4;++tt) acc[tt]=(f32x4){b1v[tt],b1v[tt],b1v[tt],b1v[tt]};
    const char* Ar=smem+L1_A_OFF+(size_t)(1-p)*ABUFB;
    const char* Sr=smem+L1_ST_OFF;
    #pragma unroll
    for (int kt=0;kt<4;++kt){
      bf16x8 a0h=*(const bf16x8*)(Sr+frdoff(c,qd,kt,0));
      bf16x8 a0l=*(const bf16x8*)(Sr+frdoff(c,qd,kt,1));
      bf16x8 a1h=*(const bf16x8*)(Ar+frdoff(c,qd,kt,0));
      bf16x8 a1l=*(const bf16x8*)(Ar+frdoff(c,qd,kt,1));
      #pragma unroll
      for (int tt=0;tt<4;++tt){
        bf16x8 bh=*(const bf16x8*)(smem+(size_t)((wv*4+tt)*4+kt)*1024+l*16);
        acc[tt]=MFMA(a0h,bh,acc[tt]);
        acc[tt]=MFMA(a0l,bh,acc[tt]);
        acc[tt]=MFMA(a0h,wil[tt*4+kt],acc[tt]);
        acc[tt]=MFMA(a1h,whh[tt*4+kt],acc[tt]);
        acc[tt]=MFMA(a1l,whh[tt*4+kt],acc[tt]);
        acc[tt]=MFMA(a1h,whl[tt*4+kt],acc[tt]);
      }
    }
    char* Aw=smem+L1_A_OFF+(size_t)p*ABUFB;
    #pragma unroll
    for (int j=0;j<4;++j){
      float cn=sigm(acc[1][j])*c1[j]+sigm(acc[0][j])*tanhx(acc[2][j]); c1[j]=cn;
      float hn=sigm(acc[3][j])*tanhx(cn);
      int row=qd*4+j;
      __bf16 hh=(__bf16)hn;
      *(__bf16*)(Aw+aoff(row,hc))=hh;
      *(__bf16*)(Aw+aoff(row,hc+128))=(__bf16)(hn-(float)hh);
      if (t==chunkLen-1){
        stf[(size_t)(blk*4+2)*2048+row*128+hc]=hn;
        stf[(size_t)(blk*4+3)*2048+row*128+hc]=cn;
      }
    }
    __syncthreads();
  }
}

// ======================= decoder (200 autoregressive steps) =======================
__global__ void __launch_bounds__(512,1)
k_dec(const float* __restrict__ xh, const float* __restrict__ pprm,
      const float* __restrict__ dwihp, const float* __restrict__ dwhh,
      const float* __restrict__ dbih, const float* __restrict__ dbhh,
      const float* __restrict__ pw, const float* __restrict__ pb,
      const float* __restrict__ ow, const float* __restrict__ ob,
      const float* __restrict__ wsf, float* __restrict__ out,
      unsigned long long stageFloats)
{
  extern __shared__ char smem[];
  const int tid=threadIdx.x, wv=tid>>6, l=tid&63, c=l&15, qd=l>>4;
  const int hc=wv*16+c, blk=blockIdx.x, r0=blk*16;
  const float* stf = wsf + stageFloats;
  bf16x8 whi[16], wlo[16];
  #pragma unroll
  for (int tt=0;tt<4;++tt)
    #pragma unroll
    for (int kt=0;kt<4;++kt){
      const float* s=dwhh+(size_t)(tt*128+hc)*128+kt*32+qd*8;
      float4 a=*(const float4*)s, b=*(const float4*)(s+4);
      whi[tt*4+kt]=hi8(a,b); wlo[tt*4+kt]=lo8(a,b,whi[tt*4+kt]);
    }
  bf16x8 owh[4], owl[4];
  #pragma unroll
  for (int kt=0;kt<4;++kt){
    int cc=(c<2)?c:0;
    const float* s=ow+cc*128+kt*32+qd*8;
    float4 a=*(const float4*)s, b=*(const float4*)(s+4);
    if (c>=2){ a=(float4){0,0,0,0}; b=(float4){0,0,0,0}; }
    owh[kt]=hi8(a,b); owl[kt]=lo8(a,b,owh[kt]);
  }
  float ob0=ob[0], ob1=ob[1];
  float prm[4][3];
  #pragma unroll
  for (int j=0;j<4;++j){
    size_t r=(size_t)(r0+qd*4+j);
    prm[j][0]=pprm[r*3+0]; prm[j][1]=pprm[r*3+1]; prm[j][2]=pprm[r*3+2];
  }
  float pt[4][4], dw0[4], dw1[4];
  #pragma unroll
  for (int tt=0;tt<4;++tt){
    int g=tt*128+hc;
    float db=dbih[g]+dbhh[g];
    dw0[tt]=dwihp[g*5+0]; dw1[tt]=dwihp[g*5+1];
    #pragma unroll
    for (int j=0;j<4;++j)
      pt[tt][j]=db+prm[j][0]*dwihp[g*5+2]+prm[j][1]*dwihp[g*5+3]+prm[j][2]*dwihp[g*5+4];
  }
  const float* h1s=stf+(size_t)(blk*4+2)*2048;
  const float* c1s=stf+(size_t)(blk*4+3)*2048;
  float c1[4], cx0[4], cx1[4];
  {
    float prj0=pw[hc*3+0], prj1=pw[hc*3+1], prj2=pw[hc*3+2], prjb=pb[hc];
    char* B0=smem;
    #pragma unroll
    for (int j=0;j<4;++j){
      int row=qd*4+j;
      float hd=h1s[row*128+hc]+prm[j][0]*prj0+prm[j][1]*prj1+prm[j][2]*prj2+prjb;
      __bf16 h=(__bf16)hd;
      *(__bf16*)(B0+aoff(row,hc))=h;
      *(__bf16*)(B0+aoff(row,hc+128))=(__bf16)(hd-(float)h);
      c1[j]=c1s[row*128+hc];
      float2 xx=*(const float2*)(xh+(size_t)(r0+row)*400+398);
      cx0[j]=xx.x; cx1[j]=xx.y;
    }
  }
  __syncthreads();
  for (int s=0;s<PRED;++s){
    const int q=s&1;
    const char* Ar=smem+(size_t)q*ABUFB;
    f32x4 acc[4], accPV={0.f,0.f,0.f,0.f};
    #pragma unroll
    for (int tt=0;tt<4;++tt) acc[tt]=(f32x4){pt[tt][0],pt[tt][1],pt[tt][2],pt[tt][3]};
    #pragma unroll
    for (int kt=0;kt<4;++kt){
      bf16x8 ah=*(const bf16x8*)(Ar+frdoff(c,qd,kt,0));
      bf16x8 al=*(const bf16x8*)(Ar+frdoff(c,qd,kt,1));
      #pragma unroll
      for (int tt=0;tt<4;++tt){
        acc[tt]=MFMA(ah,whi[tt*4+kt],acc[tt]);
        acc[tt]=MFMA(al,whi[tt*4+kt],acc[tt]);
        acc[tt]=MFMA(ah,wlo[tt*4+kt],acc[tt]);
      }
      accPV=MFMA(ah,owh[kt],accPV);
      accPV=MFMA(al,owh[kt],accPV);
      accPV=MFMA(ah,owl[kt],accPV);
    }
    float cur0[4], cur1[4];
    #pragma unroll
    for (int j=0;j<4;++j){
      float pv0=__shfl(accPV[j], (l&48),   64);
      float pv1=__shfl(accPV[j], (l&48)|1, 64);
      cur0[j]= s ? (pv0+ob0) : cx0[j];
      cur1[j]= s ? (pv1+ob1) : cx1[j];
    }
    if (s && wv==0 && c<2){
      float obv=c?ob1:ob0;
      #pragma unroll
      for (int j=0;j<4;++j)
        out[(size_t)(r0+qd*4+j)*400+(s-1)*2+c]=accPV[j]+obv;
    }
    char* Aw=smem+(size_t)(1-q)*ABUFB;
    #pragma unroll
    for (int j=0;j<4;++j){
      float gi=acc[0][j]+cur0[j]*dw0[0]+cur1[j]*dw1[0];
      float gf=acc[1][j]+cur0[j]*dw0[1]+cur1[j]*dw1[1];
      float gg=acc[2][j]+cur0[j]*dw0[2]+cur1[j]*dw1[2];
      float go=acc[3][j]+cur0[j]*dw0[3]+cur1[j]*dw1[3];
      float cn=sigm(gf)*c1[j]+sigm(gi)*tanhx(gg); c1[j]=cn;
      float hn=sigm(go)*tanhx(cn);
      int row=qd*4+j;
      __bf16 hh=(__bf16)hn;
      *(__bf16*)(Aw+aoff(row,hc))=hh;
      *(__bf16*)(Aw+aoff(row,hc+128))=(__bf16)(hn-(float)hh);
    }
    __syncthreads();
  }
  {
    const char* Ar=smem+(size_t)(PRED&1)*ABUFB;
    f32x4 accPV={0.f,0.f,0.f,0.f};
    #pragma unroll
    for (int kt=0;kt<4;++kt){
      bf16x8 ah=*(const bf16x8*)(Ar+frdoff(c,qd,kt,0));
      bf16x8 al=*(const bf16x8*)(Ar+frdoff(c,qd,kt,1));
      accPV=MFMA(ah,owh[kt],accPV);
      accPV=MFMA(al,owh[kt],accPV);
      accPV=MFMA(ah,owl[kt],accPV);
    }
    if (wv==0 && c<2){
      float obv=c?ob1:ob0;
      #pragma unroll
      for (int j=0;j<4;++j)
        out[(size_t)(r0+qd*4+j)*400+(PRED-1)*2+c]=accPV[j]+obv;
    }
  }
}

extern "C" void kernel_launch(void* const* d_in, const int* in_sizes, int n_in,
                              void* d_out, int out_size, void* d_ws, size_t ws_size,
                              hipStream_t stream)
{
  (void)out_size;
  const int base = (n_in >= 19 && in_sizes[2] == 1) ? 3 : 2;
  const float* xh   = (const float*)d_in[0];
  const float* prm  = (const float*)d_in[1];
  const float* wih0 = (const float*)d_in[base+0];
  const float* whh0 = (const float*)d_in[base+1];
  const float* bih0 = (const float*)d_in[base+2];
  const float* bhh0 = (const float*)d_in[base+3];
  const float* wih1 = (const float*)d_in[base+4];
  const float* whh1 = (const float*)d_in[base+5];
  const float* bih1 = (const float*)d_in[base+6];
  const float* bhh1 = (const float*)d_in[base+7];
  const float* dwih = (const float*)d_in[base+8];
  const float* dwhh = (const float*)d_in[base+9];
  const float* dbih = (const float*)d_in[base+10];
  const float* dbhh = (const float*)d_in[base+11];
  const float* pw   = (const float*)d_in[base+12];
  const float* pb   = (const float*)d_in[base+13];
  const float* ow   = (const float*)d_in[base+14];
  const float* ob   = (const float*)d_in[base+15];
  float* wsf = (float*)d_ws;

  size_t wsFloats = ws_size / 4;
  size_t avail = (wsFloats > STATE_FLOATS) ? (wsFloats - STATE_FLOATS) : 0;
  int chunkLen = (int)(avail / ((size_t)NBLK * 2048));
  if (chunkLen > 50) chunkLen = 50;
  if (chunkLen < 1)  chunkLen = 1;
  unsigned long long stageFloats = (unsigned long long)chunkLen * NBLK * 2048;

  hipFuncSetAttribute((const void*)k_l1, hipFuncAttributeMaxDynamicSharedMemorySize, LDS_L1);

  for (int k0 = 0; k0 < TSTEPS; k0 += chunkLen){
    int len = chunkLen; if (k0 + len > TSTEPS) len = TSTEPS - k0;
    k_l0<<<NBLK,512,LDS_SMALL,stream>>>(xh, wih0, whh0, bih0, bhh0, wsf, k0, len, stageFloats);
    k_l1<<<NBLK,512,LDS_L1,stream>>>(wih1, whh1, bih1, bhh1, wsf, k0, len, stageFloats);
  }
  k_dec<<<NBLK,512,LDS_SMALL,stream>>>(xh, prm, dwih, dwhh, dbih, dbhh,
                                       pw, pb, ow, ob, wsf, (float*)d_out, stageFloats);
}